// Round 5
// baseline (376.361 us; speedup 1.0000x reference)
//
#include <hip/hip_runtime.h>
#include <math.h>

#define BB 32
#define NN 2048
#define D_IN 320
#define H1 160
#define H2 80
#define H4 5

typedef __attribute__((ext_vector_type(8))) short short8;
typedef __attribute__((ext_vector_type(4))) short short4v;
typedef __attribute__((ext_vector_type(4))) float f32x4;

__device__ inline ushort f2bf(float f) {
    union { float f; unsigned u; } v; v.f = f;
    unsigned r = v.u + 0x7fff + ((v.u >> 16) & 1);   // RNE; inputs never NaN here
    return (ushort)(r >> 16);
}
__device__ inline float bf2f(ushort u) {
    union { float f; unsigned u; } v; v.u = ((unsigned)u) << 16;
    return v.f;
}

// ---------------------------------------------------------------------------
// Prep: transpose W1/W2 to bf16  Wt1[j=160][c=320], Wt2[j=80][c=160].
// ---------------------------------------------------------------------------
__global__ __launch_bounds__(256) void prep_weights_kernel(
    const float* __restrict__ W1, const float* __restrict__ W2,
    ushort* __restrict__ Wt1, ushort* __restrict__ Wt2)
{
    const int id0 = blockIdx.x * 256 + threadIdx.x;
    const int stride = gridDim.x * 256;
    for (int i = id0; i < H1 * D_IN; i += stride) {
        const int j = i / D_IN, c = i % D_IN;
        Wt1[i] = f2bf(W1[c * H1 + j]);
    }
    for (int i = id0; i < H2 * H1; i += stride) {
        const int j = i / H1, c = i % H1;
        Wt2[i] = f2bf(W2[c * H2 + j]);
    }
}

// ---------------------------------------------------------------------------
// MFMA MLP: h2 = relu(relu(x@W1+b1)@W2+b2), bf16 16x16x32 MFMA.
// 64 rows/block, 256 thr / 4 waves. Emits bf16 h2 (pad 96), h2T, sq2.
// ---------------------------------------------------------------------------
__global__ __launch_bounds__(256) void mlp_mfma_kernel(
    const float* __restrict__ x,
    const ushort* __restrict__ Wt1, const float* __restrict__ b1,
    const ushort* __restrict__ Wt2, const float* __restrict__ b2,
    ushort* __restrict__ h2, ushort* __restrict__ h2T, float* __restrict__ sq2)
{
    constexpr int XST  = 72;
    constexpr int W1ST = 72;
    constexpr int W2ST = 168;
    constexpr int H1ST = 168;

    __shared__ __attribute__((aligned(16))) ushort h1t[64 * H1ST];  // aliases xs
    __shared__ __attribute__((aligned(16))) ushort ws1[H1 * W1ST];  // aliases Tbuf
    __shared__ __attribute__((aligned(16))) ushort ws2[H2 * W2ST];
    __shared__ float b1s[H1];
    __shared__ float b2s[H2];

    ushort* xs = h1t;

    const int t = threadIdx.x;
    const int lane = t & 63, w = t >> 6;
    const int colid = lane & 15, quad = lane >> 4;
    const int row0 = blockIdx.x * 64;
    const int b = row0 / NN, n0 = row0 % NN;

    if (t < H1) b1s[t] = b1[t];
    if (t < H2) b2s[t] = b2[t];

    for (int id = t; id < H2 * H1 / 8; id += 256) {
        const int j = id / 20, part = id % 20;
        *(short8*)&ws2[j * W2ST + part * 8] = *(const short8*)&Wt2[j * H1 + part * 8];
    }

    f32x4 c1[10];
    #pragma unroll
    for (int ns = 0; ns < 10; ++ns) c1[ns] = (f32x4){0.f, 0.f, 0.f, 0.f};

    float4 xr[4];
    short8 wr[5];
    {
        #pragma unroll
        for (int i = 0; i < 4; ++i) {
            const int id = t + i * 256, row = id >> 4, c4 = id & 15;
            xr[i] = *(const float4*)&x[(size_t)(row0 + row) * D_IN + c4 * 4];
        }
        #pragma unroll
        for (int i = 0; i < 5; ++i) {
            const int id = t + i * 256, j = id >> 3, part = id & 7;
            wr[i] = *(const short8*)&Wt1[j * D_IN + part * 8];
        }
    }

    for (int kc = 0; kc < 5; ++kc) {
        if (kc) __syncthreads();
        #pragma unroll
        for (int i = 0; i < 4; ++i) {
            const int id = t + i * 256, row = id >> 4, c4 = id & 15;
            short4v s;
            s[0] = (short)f2bf(xr[i].x); s[1] = (short)f2bf(xr[i].y);
            s[2] = (short)f2bf(xr[i].z); s[3] = (short)f2bf(xr[i].w);
            *(short4v*)&xs[row * XST + c4 * 4] = s;
        }
        #pragma unroll
        for (int i = 0; i < 5; ++i) {
            const int id = t + i * 256, j = id >> 3, part = id & 7;
            *(short8*)&ws1[j * W1ST + part * 8] = wr[i];
        }
        if (kc < 4) {
            const int k0 = (kc + 1) * 64;
            #pragma unroll
            for (int i = 0; i < 4; ++i) {
                const int id = t + i * 256, row = id >> 4, c4 = id & 15;
                xr[i] = *(const float4*)&x[(size_t)(row0 + row) * D_IN + k0 + c4 * 4];
            }
            #pragma unroll
            for (int i = 0; i < 5; ++i) {
                const int id = t + i * 256, j = id >> 3, part = id & 7;
                wr[i] = *(const short8*)&Wt1[j * D_IN + k0 + part * 8];
            }
        }
        __syncthreads();

        short8 af[2];
        #pragma unroll
        for (int kf = 0; kf < 2; ++kf)
            af[kf] = *(const short8*)&xs[(w * 16 + colid) * XST + kf * 32 + quad * 8];
        #pragma unroll
        for (int ns = 0; ns < 10; ++ns) {
            #pragma unroll
            for (int kf = 0; kf < 2; ++kf) {
                const short8 bf = *(const short8*)&ws1[(ns * 16 + colid) * W1ST + kf * 32 + quad * 8];
                c1[ns] = __builtin_amdgcn_mfma_f32_16x16x32_bf16(af[kf], bf, c1[ns], 0, 0, 0);
            }
        }
    }
    __syncthreads();

    #pragma unroll
    for (int ns = 0; ns < 10; ++ns) {
        const float bj = b1s[ns * 16 + colid];
        #pragma unroll
        for (int r = 0; r < 4; ++r)
            h1t[(w * 16 + quad * 4 + r) * H1ST + ns * 16 + colid] =
                f2bf(fmaxf(c1[ns][r] + bj, 0.f));
    }
    __asm__ volatile("s_waitcnt lgkmcnt(0)" ::: "memory");

    short8 a2[5];
    #pragma unroll
    for (int kf = 0; kf < 5; ++kf)
        a2[kf] = *(const short8*)&h1t[(w * 16 + colid) * H1ST + kf * 32 + quad * 8];

    f32x4 c2[5];
    #pragma unroll
    for (int js = 0; js < 5; ++js) {
        f32x4 acc = (f32x4){0.f, 0.f, 0.f, 0.f};
        #pragma unroll
        for (int kf = 0; kf < 5; ++kf) {
            const short8 wb = *(const short8*)&ws2[(js * 16 + colid) * W2ST + kf * 32 + quad * 8];
            acc = __builtin_amdgcn_mfma_f32_16x16x32_bf16(a2[kf], wb, acc, 0, 0, 0);
        }
        c2[js] = acc;
    }
    __syncthreads();

    ushort* Tbuf = ws1;
    float rsq[4] = {0.f, 0.f, 0.f, 0.f};
    #pragma unroll
    for (int js = 0; js < 5; ++js) {
        const float bj = b2s[js * 16 + colid];
        #pragma unroll
        for (int r = 0; r < 4; ++r) {
            const ushort u = f2bf(fmaxf(c2[js][r] + bj, 0.f));
            const float vv = bf2f(u);
            rsq[r] += vv * vv;
            h2[(size_t)(row0 + w * 16 + quad * 4 + r) * 96 + js * 16 + colid] = u;
            Tbuf[(js * 16 + colid) * 72 + w * 16 + quad * 4 + r] = u;
        }
    }
    {
        const short8 z8 = {0, 0, 0, 0, 0, 0, 0, 0};
        if (t < 128) {
            const int row = t >> 1, part = t & 1;
            *(short8*)&h2[(size_t)(row0 + row) * 96 + 80 + part * 8] = z8;
        }
        if (t < 128) {
            const int row = 80 + (t >> 3), part = t & 7;
            *(short8*)&Tbuf[row * 72 + part * 8] = z8;
        }
    }
    #pragma unroll
    for (int m = 1; m <= 8; m <<= 1)
        #pragma unroll
        for (int r = 0; r < 4; ++r) rsq[r] += __shfl_xor(rsq[r], m);
    if (colid == 0) {
        #pragma unroll
        for (int r = 0; r < 4; ++r)
            sq2[(size_t)row0 + w * 16 + quad * 4 + r] = rsq[r];
    }
    __syncthreads();
    for (int id = t; id < 96 * 8; id += 256) {
        const int row = id >> 3, part = id & 7;
        *(short8*)&h2T[((size_t)b * 96 + row) * NN + n0 + part * 8] =
            *(const short8*)&Tbuf[row * 72 + part * 8];
    }
}

// ---------------------------------------------------------------------------
// Flash-attention graph conv, register-chained (no P/O LDS round trips):
//   S^T via mfma_16x16x32(A=K, B=Q)  -> C-layout = Sᵀ[key=4q+r][qrow=colid]
//   p = exp2(2*S - sq_m - sq_n), packed in-register -> B-operand of
//   mfma_16x16x16bf16_1k (B[n=colid][k=4q+j] == Sᵀ C-layout) for O += PV
//   Oᵀ C-layout == x16 A-operand layout -> projection also register-direct.
// Block: 256 thr / 4 waves; 64 Q-rows per block; keys in 64-chunks.
// ---------------------------------------------------------------------------
template<int C_PAD, int C_IN_REAL, int C_OUT, int JS, bool HAS_OUT, bool DO_MEAN>
__global__ __launch_bounds__(256) void attn_conv_kernel(
    const ushort* __restrict__ h, const ushort* __restrict__ hT,
    const float* __restrict__ sqg,
    const float* __restrict__ W, const float* __restrict__ bias,
    ushort* __restrict__ ho, ushort* __restrict__ hoT, float* __restrict__ sqo,
    float* __restrict__ mean_out)
{
    constexpr int KF  = C_PAD / 32;      // 32-chunks of channels (3 or 2)
    constexpr int CS  = C_PAD / 16;      // 16-chunks of channels (6 or 4)
    constexpr int KST = C_PAD + 8;       // Krow LDS stride (bf16)
    constexpr int VST = 64 + 8;          // Vcol LDS stride
    constexpr int POS = C_PAD + 8;       // Wt stride
    constexpr int NKLD = (64 * C_PAD / 8) / 256;
    constexpr int NVLD = (C_PAD * 8) / 256;

    __shared__ __attribute__((aligned(16))) ushort Krow[64 * KST];
    __shared__ __attribute__((aligned(16))) ushort Vcol[C_PAD * VST];
    __shared__ __attribute__((aligned(16))) ushort Wt[JS * 16 * POS];
    __shared__ float biasS[JS * 16];
    __shared__ float sqs[64];

    const int t = threadIdx.x;
    const int lane = t & 63, w = t >> 6;
    const int colid = lane & 15, quad = lane >> 4;
    const int b = blockIdx.x >> 5;
    const int n0blk = (blockIdx.x & 31) * 64;

    const float LOG2E  = 1.44269504088896340736f;
    const float TWOL2E = 2.88539008177792681472f;

    for (int id = t; id < JS * 16 * C_PAD; id += 256) {
        const int j = id / C_PAD, c = id % C_PAD;
        const float v = (j < C_OUT && c < C_IN_REAL) ? W[c * C_OUT + j] : 0.f;
        Wt[j * POS + c] = f2bf(v);
    }
    if (t < JS * 16) biasS[t] = (t < C_OUT) ? bias[t] : 0.f;

    // Q frags (x32 B-operand): lane holds Q[qrow=colid][k=quad*8+j] per chunk
    short8 qf[KF];
    {
        const ushort* qrow = h + (size_t)((size_t)b * NN + n0blk + w * 16 + colid) * C_PAD;
        #pragma unroll
        for (int kf = 0; kf < KF; ++kf)
            qf[kf] = *(const short8*)&qrow[kf * 32 + quad * 8];
    }
    // per-lane row bias: |h_qrow|^2 * log2e  (qrow = colid within wave)
    const float sqnQL = sqg[(size_t)b * NN + n0blk + w * 16 + colid] * LOG2E;

    f32x4 o[CS];
    #pragma unroll
    for (int cs = 0; cs < CS; ++cs) o[cs] = (f32x4){0.f, 0.f, 0.f, 0.f};
    float rs = 0.f;                            // per-lane denominator part

    // prefetch tile 0
    short8 kreg[NKLD], vreg[NVLD];
    float sqreg = 0.f;
    {
        const ushort* hsrc = h + (size_t)((size_t)b * NN) * C_PAD;
        #pragma unroll
        for (int i = 0; i < NKLD; ++i)
            kreg[i] = *(const short8*)&hsrc[(t + i * 256) * 8];
        #pragma unroll
        for (int i = 0; i < NVLD; ++i) {
            const int id = t + i * 256, c = id >> 3, pt = id & 7;
            vreg[i] = *(const short8*)&hT[((size_t)b * C_PAD + c) * NN + pt * 8];
        }
        if (t < 64) sqreg = sqg[(size_t)b * NN + t];
    }

    for (int n0 = 0; n0 < NN; n0 += 64) {
        if (n0) __syncthreads();
        #pragma unroll
        for (int i = 0; i < NKLD; ++i) {
            const int id = t + i * 256;
            const int row = id / (C_PAD / 8), pt = id % (C_PAD / 8);
            *(short8*)&Krow[row * KST + pt * 8] = kreg[i];
        }
        #pragma unroll
        for (int i = 0; i < NVLD; ++i) {
            const int id = t + i * 256, c = id >> 3, pt = id & 7;
            *(short8*)&Vcol[c * VST + pt * 8] = vreg[i];
        }
        if (t < 64) sqs[t] = sqreg;
        if (n0 + 64 < NN) {
            const int n1 = n0 + 64;
            const ushort* hsrc = h + (size_t)((size_t)b * NN + n1) * C_PAD;
            #pragma unroll
            for (int i = 0; i < NKLD; ++i)
                kreg[i] = *(const short8*)&hsrc[(t + i * 256) * 8];
            #pragma unroll
            for (int i = 0; i < NVLD; ++i) {
                const int id = t + i * 256, c = id >> 3, pt = id & 7;
                vreg[i] = *(const short8*)&hT[((size_t)b * C_PAD + c) * NN + n1 + pt * 8];
            }
            if (t < 64) sqreg = sqg[(size_t)b * NN + n1 + t];
        }
        __syncthreads();

        // 4 independent 16-key chunks, fully register-chained
        #pragma unroll
        for (int nc = 0; nc < 4; ++nc) {
            // S^T: A = K rows (lane: key=nc*16+colid), B = Q
            f32x4 st = (f32x4){0.f, 0.f, 0.f, 0.f};
            #pragma unroll
            for (int cc = 0; cc < KF; ++cc) {
                const short8 kf_ = *(const short8*)&Krow[(nc * 16 + colid) * KST + cc * 32 + quad * 8];
                st = __builtin_amdgcn_mfma_f32_16x16x32_bf16(kf_, qf[cc], st, 0, 0, 0);
            }
            // exp2 + pack -> x16 B-operand (keys nc*16+quad*4+r, qrow colid)
            short4v pk;
            #pragma unroll
            for (int r = 0; r < 4; ++r) {
                const float sm = sqs[nc * 16 + quad * 4 + r];
                const float p = exp2f(fmaf(st[r], TWOL2E, fmaf(sm, -LOG2E, -sqnQL)));
                rs += p;
                pk[r] = (short)f2bf(p);
            }
            // O^T += V^T @ P^T  (A = V^T rows: c=cs*16+colid, k=key)
            #pragma unroll
            for (int cs = 0; cs < CS; ++cs) {
                const short4v vf = *(const short4v*)&Vcol[(cs * 16 + colid) * VST + nc * 16 + quad * 4];
                o[cs] = __builtin_amdgcn_mfma_f32_16x16x16bf16_1k(vf, pk, o[cs], 0, 0, 0);
            }
        }
    }
    __syncthreads();                           // Krow free for reuse as Tbuf

    // denominator for qrow=colid: sum over the 4 quads
    rs += __shfl_xor(rs, 16);
    rs += __shfl_xor(rs, 32);
    const float rinv = 1.f / rs;

    // O^T C-layout == x16 A-operand layout: pack in-register
    short4v oaf[CS];
    #pragma unroll
    for (int cs = 0; cs < CS; ++cs)
        #pragma unroll
        for (int r = 0; r < 4; ++r)
            oaf[cs][r] = (short)f2bf(o[cs][r] * rinv);

    ushort* Tbuf = Krow;
    float rsq[4] = {0.f, 0.f, 0.f, 0.f};
    float msum = 0.f;

    #pragma unroll
    for (int js = 0; js < (HAS_OUT ? 4 : JS); ++js) {
        float v[4];
        if (js < JS) {
            f32x4 acc = (f32x4){0.f, 0.f, 0.f, 0.f};
            #pragma unroll
            for (int cs = 0; cs < CS; ++cs) {
                const short4v wf = *(const short4v*)&Wt[(js * 16 + colid) * POS + cs * 16 + quad * 4];
                acc = __builtin_amdgcn_mfma_f32_16x16x16bf16_1k(oaf[cs], wf, acc, 0, 0, 0);
            }
            const float bj = biasS[js * 16 + colid];
            #pragma unroll
            for (int r = 0; r < 4; ++r) v[r] = fmaxf(acc[r] + bj, 0.f);
        } else {
            #pragma unroll
            for (int r = 0; r < 4; ++r) v[r] = 0.f;
        }
        if (HAS_OUT) {
            #pragma unroll
            for (int r = 0; r < 4; ++r) {
                const int grow = n0blk + w * 16 + quad * 4 + r;
                ho[(size_t)((size_t)b * NN + grow) * 64 + js * 16 + colid] = f2bf(v[r]);
                Tbuf[(js * 16 + colid) * 72 + w * 16 + quad * 4 + r] = f2bf(v[r]);
                rsq[r] += v[r] * v[r];
            }
        }
        if (DO_MEAN) {
            #pragma unroll
            for (int r = 0; r < 4; ++r) msum += v[r];
        }
    }

    if (HAS_OUT) {
        #pragma unroll
        for (int m = 1; m <= 8; m <<= 1)
            #pragma unroll
            for (int r = 0; r < 4; ++r) rsq[r] += __shfl_xor(rsq[r], m);
        if (colid == 0) {
            #pragma unroll
            for (int r = 0; r < 4; ++r)
                sqo[(size_t)b * NN + n0blk + w * 16 + quad * 4 + r] = rsq[r];
        }
        __syncthreads();
        for (int id = t; id < 64 * 8; id += 256) {
            const int row = id >> 3, part = id & 7;
            *(short8*)&hoT[((size_t)b * 64 + row) * NN + n0blk + part * 8] =
                *(const short8*)&Tbuf[row * 72 + part * 8];
        }
    }
    if (DO_MEAN) {
        msum += __shfl_xor(msum, 16);
        msum += __shfl_xor(msum, 32);
        if (lane < C_OUT) atomicAdd(&mean_out[b * C_OUT + lane], msum * (1.f / NN));
    }
}

// ---------------------------------------------------------------------------
// Final classifier + softmax over 2 logits.
// ---------------------------------------------------------------------------
__global__ __launch_bounds__(64) void final_kernel(
    const float* __restrict__ mean, const float* __restrict__ Wf,
    const float* __restrict__ bf, float* __restrict__ out)
{
    const int t = threadIdx.x;
    const int b = t >> 1, k = t & 1;
    float acc = bf[k];
    #pragma unroll
    for (int c = 0; c < H4; ++c) acc += mean[b * H4 + c] * Wf[c * 2 + k];
    const float other = __shfl_xor(acc, 1);
    const float mx = fmaxf(acc, other);
    const float e  = __expf(acc - mx);
    const float eo = __expf(other - mx);
    out[t] = e / (e + eo);
}

extern "C" void kernel_launch(void* const* d_in, const int* in_sizes, int n_in,
                              void* d_out, int out_size, void* d_ws, size_t ws_size,
                              hipStream_t stream) {
    const float* x   = (const float*)d_in[0];
    const float* W1  = (const float*)d_in[1];
    const float* b1  = (const float*)d_in[2];
    const float* W2  = (const float*)d_in[3];
    const float* b2  = (const float*)d_in[4];
    const float* Wg1 = (const float*)d_in[5];
    const float* bg1 = (const float*)d_in[6];
    const float* Wg2 = (const float*)d_in[7];
    const float* bg2 = (const float*)d_in[8];
    const float* Wf  = (const float*)d_in[9];
    const float* bf  = (const float*)d_in[10];

    ushort* h2  = (ushort*)d_ws;                         // [B*N][96] bf16
    ushort* h2T = h2  + (size_t)BB * NN * 96;            // [B][96][N] bf16
    float*  sq2 = (float*)(h2T + (size_t)BB * 96 * NN);  // [B*N]
    ushort* h3  = (ushort*)(sq2 + (size_t)BB * NN);      // [B*N][64] bf16
    ushort* h3T = h3  + (size_t)BB * NN * 64;            // [B][64][N] bf16
    float*  sq3 = (float*)(h3T + (size_t)BB * 64 * NN);  // [B*N]
    float*  meanb = sq3 + (size_t)BB * NN;               // [B*5]
    ushort* Wt1 = (ushort*)(((uintptr_t)(meanb + BB * H4) + 15) & ~(uintptr_t)15);
    ushort* Wt2 = Wt1 + (size_t)H1 * D_IN;               // [80][160] bf16

    hipMemsetAsync(meanb, 0, BB * H4 * sizeof(float), stream);

    prep_weights_kernel<<<64, 256, 0, stream>>>(W1, W2, Wt1, Wt2);
    mlp_mfma_kernel<<<BB * NN / 64, 256, 0, stream>>>(x, Wt1, b1, Wt2, b2, h2, h2T, sq2);
    attn_conv_kernel<96, 80, 40, 3, true,  false><<<BB * NN / 64, 256, 0, stream>>>(
        h2, h2T, sq2, Wg1, bg1, h3, h3T, sq3, nullptr);
    attn_conv_kernel<64, 40, 5, 1, false, true><<<BB * NN / 64, 256, 0, stream>>>(
        h3, h3T, sq3, Wg2, bg2, nullptr, nullptr, nullptr, meanb);
    final_kernel<<<1, 64, 0, stream>>>(meanb, Wf, bf, (float*)d_out);
}